// Round 9
// baseline (144.972 us; speedup 1.0000x reference)
//
#include <hip/hip_runtime.h>
#include <stdint.h>
#include <math.h>

#pragma clang fp contract(off)

#define N_ROWS 1048576
#define N_CLS  20
#define K_TOP  2000
#define CAND_MAX 4096
#define H_COPIES 4
#define MAGIC 0x5AD0C0DEu
#define NBLK 1024

// scal slots (dwords) -- all inside the zeroed region
#define SC_CNT   0
#define SC_MAXK  1
#define SC_DONE  2   // maskscan done-counter
#define SC_BAR1  3   // fused-kernel barrier-1 arrival counter
#define SC_FLAG1 4   // barrier-1 release word: (b0<<16)|R1  (nonzero)
#define SC_BAR2  5   // barrier-2 arrival counter
#define SC_FLAG2 6   // barrier-2 release word: T+1          (nonzero)

// ws layout
static constexpr size_t OFF_HIST1 = 0;                             // u32[4*256] -- zero region start
static constexpr size_t OFF_HIST2 = OFF_HIST1 + 4096;              // u32[4*256]
static constexpr size_t OFF_SCAL  = OFF_HIST2 + 4096;              // u32[16]
static constexpr size_t OFF_GRP   = OFF_SCAL + 64;                 // u64[32]    -- zero region end (2128 dwords)
static constexpr size_t OFF_ZIN   = OFF_GRP + 256;                 // u32[8] MAGIC words (reset by last kernel)
static constexpr size_t OFF_CAND  = OFF_ZIN + 256;                 // u64[CAND_MAX]
static constexpr size_t OFF_MASK  = OFF_CAND + 8ull * CAND_MAX;    // u64[K_TOP*32]

__device__ __forceinline__ uint32_t mono_key(float f) {
    uint32_t u = __float_as_uint(f);
    return u ^ ((u & 0x80000000u) ? 0xFFFFFFFFu : 0x80000000u);
}
__device__ __forceinline__ float mono_inv(uint32_t k) {
    uint32_t u = (k & 0x80000000u) ? (k ^ 0x80000000u) : ~k;
    return __uint_as_float(u);
}

// ---- D1: fused score + hist1 + (grid barrier) + hist2 + (grid barrier) + compact.
//      1024 blocks x 256 thr, ALL co-resident (23.6 KB LDS -> 6 blocks/CU >= 4 needed;
//      launch_bounds(256,4) caps VGPR <= 128 -> 4 waves/SIMD). Mono-keys + argmax kept
//      in registers across barriers -> no mkey/cls global arrays at all. Barriers are
//      atomic-only (drain + counter); release flag CARRIES the find result, computed
//      once by the last-arriving block (no all-blocks atomic-fetch storm).
__global__ __launch_bounds__(256, 4) void k_fused(const float* __restrict__ logits,
                                                  uint32_t* __restrict__ hist1,   // zero region base
                                                  uint32_t* __restrict__ hist2,
                                                  uint32_t* __restrict__ scal,
                                                  uint32_t* __restrict__ zin,
                                                  unsigned long long* __restrict__ cand) {
    __shared__ uint64_t stg64[2688];       // 21504 B: phase A staging / phase C compact buffer
    __shared__ uint32_t hh[256];
    __shared__ uint32_t sfx[256];
    __shared__ uint32_t bc[2];
    __shared__ uint32_t cnt, gbase;
    __shared__ int islast;
    uint32_t* stage = (uint32_t*)stg64;
    int t = threadIdx.x, b = blockIdx.x;
    int lane = t & 63;

    // zero phase: blocks 0..7 zero the 2128-dword region via device atomics, publish MAGIC.
    if (b < 8) {
        uint32_t zd = atomicExch(&hist1[b * 256 + t], 0u);
        if (b == 7 && t < 80) zd += atomicExch(&hist1[2048 + t], 0u);
        asm volatile("" :: "v"(zd));
        asm volatile("s_waitcnt vmcnt(0)" ::: "memory");
        __syncthreads();
        if (t == 0) atomicExch(&zin[b], MAGIC);
    }

    if (t == 0) cnt = 0;
    hh[t] = 0;
    __syncthreads();

    // ---- phase A: score (LDS-staged coalesced loads), keys/cls kept in registers
    uint32_t mk[4]; uint32_t cl[4];
    size_t rowbase0 = (size_t)b * 1024;
    for (int g = 0; g < 4; ++g) {
        const float4* src = (const float4*)(logits + (rowbase0 + (size_t)g * 256) * N_CLS);
#pragma unroll
        for (int q = 0; q < 5; ++q) {
            float4 v = src[q * 256 + t];            // fully coalesced 16B/lane
            int w0 = (q * 256 + t) * 4;
#pragma unroll
            for (int e = 0; e < 4; ++e) {
                int w = w0 + e;                     // stage addr = w + w/20  (row pad 20->21)
                stage[w + ((w * 52429u) >> 20)] = __float_as_uint((&v.x)[e]);
            }
        }
        __syncthreads();
        const uint32_t* row = &stage[t * 21];
        float m = __uint_as_float(row[0]); int ci = 0;
#pragma unroll
        for (int c = 1; c < 20; ++c) {
            float v = __uint_as_float(row[c]);
            if (v > m) { m = v; ci = c; }
        }
        mk[g] = mono_key(m);
        cl[g] = (uint32_t)ci;
        atomicAdd(&hh[mk[g] >> 24], 1u);
        __syncthreads();
    }

    // wait for zeroing (normally long done: zero ~1us << compute ~13us)
    for (;;) {
        int ok = 1;
        if (t < 8) ok = (atomicAdd(&zin[t], 0u) == MAGIC) ? 1 : 0;
        if (__syncthreads_count(ok) == 256) break;
        __builtin_amdgcn_s_sleep(16);
    }

    // publish stage-1 histogram (4 spread copies), drain before arrival
    uint32_t hv = hh[t], dm = 0;
    if (hv) dm = atomicAdd(&hist1[(b & 3) * 256 + t], hv);
    asm volatile("" :: "v"(dm));
    asm volatile("s_waitcnt vmcnt(0)" ::: "memory");
    __syncthreads();

    // ---- barrier 1: last-arriving block computes the stage-1 find, publishes (b0<<16)|R1
    if (t == 0) {
        uint32_t old = atomicAdd(&scal[SC_BAR1], 1u);
        islast = (old == (uint32_t)(NBLK - 1)) ? 1 : 0;
    }
    __syncthreads();
    if (islast) {
        uint32_t h = 0;
#pragma unroll
        for (int k = 0; k < H_COPIES; ++k) h += atomicAdd(&hist1[k * 256 + t], 0u);
        sfx[t] = h;
        __syncthreads();
        for (int off = 1; off < 256; off <<= 1) {
            uint32_t v = (t + off < 256) ? sfx[t + off] : 0;
            __syncthreads();
            sfx[t] += v;
            __syncthreads();
        }
        if (sfx[t] >= (uint32_t)K_TOP && (t == 255 || sfx[t + 1] < (uint32_t)K_TOP)) {
            uint32_t R1 = (uint32_t)K_TOP - (sfx[t] - h);
            atomicExch(&scal[SC_FLAG1], ((uint32_t)t << 16) | R1);   // nonzero (R1>=1)
        }
    }
    for (;;) {
        if (t == 0) bc[0] = atomicAdd(&scal[SC_FLAG1], 0u);
        __syncthreads();
        if (bc[0] != 0u) break;
        __builtin_amdgcn_s_sleep(32);
    }
    uint32_t b0 = bc[0] >> 16, R1 = bc[0] & 0xFFFFu;

    // ---- phase B: stage-2 restricted histogram from registers
    hh[t] = 0;
    __syncthreads();
#pragma unroll
    for (int g = 0; g < 4; ++g)
        if ((mk[g] >> 24) == b0) atomicAdd(&hh[(mk[g] >> 16) & 0xFFu], 1u);
    __syncthreads();
    hv = hh[t]; dm = 0;
    if (hv) dm = atomicAdd(&hist2[(b & 3) * 256 + t], hv);
    asm volatile("" :: "v"(dm));
    asm volatile("s_waitcnt vmcnt(0)" ::: "memory");
    __syncthreads();

    // ---- barrier 2: last block computes stage-2 find, publishes T+1
    if (t == 0) {
        uint32_t old = atomicAdd(&scal[SC_BAR2], 1u);
        islast = (old == (uint32_t)(NBLK - 1)) ? 1 : 0;
    }
    __syncthreads();
    if (islast) {
        uint32_t h = 0;
#pragma unroll
        for (int k = 0; k < H_COPIES; ++k) h += atomicAdd(&hist2[k * 256 + t], 0u);
        sfx[t] = h;
        __syncthreads();
        for (int off = 1; off < 256; off <<= 1) {
            uint32_t v = (t + off < 256) ? sfx[t + off] : 0;
            __syncthreads();
            sfx[t] += v;
            __syncthreads();
        }
        if (sfx[t] >= R1 && (t == 255 || sfx[t + 1] < R1)) {
            uint32_t t16 = (b0 << 8) | (uint32_t)t;
            uint32_t T = (t16 > 0) ? (t16 - 1) : 0;  // -1 bin safety: rounded-sigmoid ties
            atomicExch(&scal[SC_FLAG2], T + 1u);     // nonzero
        }
    }
    for (;;) {
        if (t == 0) bc[1] = atomicAdd(&scal[SC_FLAG2], 0u);
        __syncthreads();
        if (bc[1] != 0u) break;
        __builtin_amdgcn_s_sleep(32);
    }
    uint32_t T = bc[1] - 1u;

    // ---- phase C: compact from registers ((mk>>16) >= T); cls packed in bits [24:20]
    for (int g = 0; g < 4; ++g) {
        uint32_t u = mk[g];
        bool pass = (u >> 16) >= T;
        unsigned long long bal = __ballot(pass);
        if (bal) {
            uint32_t wbase = 0;
            if (lane == 0) wbase = atomicAdd(&cnt, (uint32_t)__popcll(bal));
            wbase = __shfl(wbase, 0);
            if (pass) {
                uint32_t pos = wbase + (uint32_t)__popcll(bal & ((1ull << lane) - 1ull));
                uint32_t rowid = (uint32_t)(rowbase0 + (size_t)g * 256 + t);
                if (pos < 1024) stg64[pos] = ((uint64_t)u << 32) | (cl[g] << 20) | rowid;
            }
        }
    }
    __syncthreads();
    uint32_t n = cnt; if (n > 1024) n = 1024;
    if (t == 0 && n) gbase = atomicAdd(&scal[SC_CNT], n);
    __syncthreads();
    if (n) {
        uint32_t gb = gbase;
        for (uint32_t i = t; i < n; i += 256) {
            uint32_t pos = gb + i;
            if (pos < (uint32_t)CAND_MAX) cand[pos] = stg64[i];  // plain store; boundary = coherence
        }
    }
}

// ---- D2: rank-by-counting, j-PARALLEL (proven R7/R8): wave-per-candidate, lanes
//      split the scan, shuffle-reduce. Key low32 = row (tie-break: score desc, idx asc).
__global__ __launch_bounds__(256) void k_rank(const unsigned long long* __restrict__ cand,
                                              uint32_t* __restrict__ scal,
                                              const float* __restrict__ deltas,
                                              const float* __restrict__ locs,
                                              const int* __restrict__ stridep,
                                              float* __restrict__ out) {
    __shared__ uint64_t keys[CAND_MAX];
    __shared__ uint8_t carr[CAND_MAX];
    int t = threadIdx.x;
    uint32_t M = scal[SC_CNT];
    if (M > (uint32_t)CAND_MAX) M = CAND_MAX;
    for (uint32_t i = t; i < M; i += 256) {
        unsigned long long cd = cand[i];
        uint32_t mk = (uint32_t)(cd >> 32);
        uint32_t row = (uint32_t)cd & (N_ROWS - 1);
        float m = mono_inv(mk);
        float ef = (float)exp(-(double)m);          // ~correctly-rounded fp32 expf
        float s = 1.0f / (1.0f + ef);
        keys[i] = ((uint64_t)(~__float_as_uint(s)) << 32) | row;
        carr[i] = (uint8_t)((cd >> 20) & 0x1Fu);
    }
    __syncthreads();
    int wid = t >> 6, lane = t & 63;
    float stridef = (float)(*stridep);
    float wmx = -3.4e38f;
    for (uint32_t c = (uint32_t)blockIdx.x * 4 + wid; c < M; c += 256) {  // 64 blocks * 4 waves
        uint64_t myk = keys[c];
        uint32_t r = 0;
        for (uint32_t j = lane; j < M; j += 64) r += (keys[j] < myk) ? 1u : 0u;
#pragma unroll
        for (int o = 32; o > 0; o >>= 1) r += __shfl_down(r, o);
        if (lane == 0 && r < (uint32_t)K_TOP) {
            uint32_t row = (uint32_t)myk & (N_ROWS - 1);
            float s = __uint_as_float(~(uint32_t)(myk >> 32));
            float4 dl = ((const float4*)deltas)[row];
            float2 lc = ((const float2*)locs)[row];
            float d0 = dl.x * stridef, d1 = dl.y * stridef, d2 = dl.z * stridef, d3 = dl.w * stridef;
            float b0f = lc.x - d0, b1f = lc.y - d1, b2f = lc.x + d2, b3f = lc.y + d3;
            float4 bx = { b0f, b1f, b2f, b3f };
            *(float4*)&out[4 * r] = bx;
            out[8000 + r] = s;
            out[10000 + r] = (float)carr[c];
            wmx = fmaxf(wmx, fmaxf(fmaxf(b0f, b1f), fmaxf(b2f, b3f)));
        }
    }
    if (lane == 0) atomicMax(&scal[SC_MAXK], mono_key(wmx));
}

// ---- D3: pairwise suppression mask (quirky IoU replicated exactly) + fused scan.
//      Atomic-only cross-block handoff (proven R5/R7/R8). Tail: reset zin MAGIC words.
__global__ __launch_bounds__(256) void k_maskscan(const float* __restrict__ out_ro,
                                                  uint32_t* __restrict__ scal,
                                                  uint64_t* __restrict__ mask,
                                                  unsigned long long* __restrict__ grp,
                                                  uint32_t* __restrict__ zin,
                                                  float* __restrict__ out) {
    __shared__ int lastdone;
    int t = threadIdx.x;
    int lane = t & 63;
    int i = blockIdx.x * 4 + (t >> 6);              // 2000 waves total
    float off1 = mono_inv(scal[SC_MAXK]) + 1.0f;    // max_coord + 1 (prev dispatch, coherent)
    float4 boxi = *(const float4*)&out_ro[4 * i];
    float oi = out_ro[10000 + i] * off1;
    float x1i = boxi.x + oi, y2i = boxi.y + oi, x2i = boxi.z + oi, y1i = boxi.w + oi;
    float ai = (x2i - x1i) * (y2i - y1i);
    unsigned long long dummy = 0;
    for (int jb = 0; jb < 32; ++jb) {
        int j = jb * 64 + lane;
        bool sup = false;
        if (j < K_TOP && j > i) {
            float4 boxj = *(const float4*)&out_ro[4 * j];
            float oj = out_ro[10000 + j] * off1;
            float x1j = boxj.x + oj, y2j = boxj.y + oj, x2j = boxj.z + oj, y1j = boxj.w + oj;
            float aj = (x2j - x1j) * (y2j - y1j);
            float xx1 = fmaxf(x1i, x1j);
            float yy1 = fminf(y1i, y1j);
            float xx2 = fminf(x2i, x2j);
            float yy2 = fmaxf(y2i, y2j);
            float inter = fabsf(xx2 - xx1) * fabsf(yy2 - yy1);
            float iou = inter / ((ai + aj) - inter);
            sup = iou > 0.5f;
        }
        unsigned long long bits = __ballot(sup);
        if (lane == 0) {
            dummy += atomicExch(&mask[(size_t)i * 32 + jb], bits);
            if (bits) dummy += atomicOr(&grp[i >> 6], 1ull << (i & 63));
        }
    }
    asm volatile("" :: "v"(dummy));                 // force atomic returns (vmcnt drained)
    asm volatile("s_waitcnt vmcnt(0) lgkmcnt(0)" ::: "memory");
    __syncthreads();
    if (t == 0) {
        unsigned old = atomicAdd(&scal[SC_DONE], 1u);
        lastdone = (old == (unsigned)(gridDim.x - 1)) ? 1 : 0;
    }
    __syncthreads();
    if (!lastdone) return;

    if (t < 64) {
        int l = t;                                  // lane w<32 holds active word w
        uint64_t g = (l < 32) ? atomicOr(&grp[l], 0ull) : 0ull;
        uint64_t active = ~0ull;
        if (__ballot(g != 0ull)) {
            for (int gg = 0; gg < 32; ++gg) {
                uint64_t nz = __shfl(g, gg);
                while (nz) {
                    int b = __ffsll((long long)nz) - 1;
                    nz &= nz - 1;
                    int ii = gg * 64 + b;
                    uint64_t aw = __shfl(active, gg);
                    bool kept = (aw >> b) & 1ull;
                    uint64_t m = (l < 32) ? atomicOr(&mask[(size_t)ii * 32 + l], 0ull) : 0ull;
                    if (kept) active &= ~m;
                }
            }
        }
        if (l < 32) {
            int limit = K_TOP - l * 64;
            int nvec = limit < 64 ? limit / 4 : 16;
            for (int v = 0; v < nvec; ++v) {
                float4 f;
                f.x = ((active >> (4 * v + 0)) & 1ull) ? 1.0f : 0.0f;
                f.y = ((active >> (4 * v + 1)) & 1ull) ? 1.0f : 0.0f;
                f.z = ((active >> (4 * v + 2)) & 1ull) ? 1.0f : 0.0f;
                f.w = ((active >> (4 * v + 3)) & 1ull) ? 1.0f : 0.0f;
                *(float4*)&out[12000 + l * 64 + 4 * v] = f;
            }
        }
    }
    // reset MAGIC words for the next replay (zeroed state is what D1 expects)
    if (t < 8) atomicExch(&zin[t], 0u);
}

extern "C" void kernel_launch(void* const* d_in, const int* in_sizes, int n_in,
                              void* d_out, int out_size, void* d_ws, size_t ws_size,
                              hipStream_t stream) {
    const float* deltas = (const float*)d_in[0];
    const float* locs   = (const float*)d_in[1];
    const float* logits = (const float*)d_in[2];
    const int*   stridep = (const int*)d_in[3];
    float* out = (float*)d_out;
    char* ws = (char*)d_ws;

    uint32_t* hist1 = (uint32_t*)(ws + OFF_HIST1);
    uint32_t* hist2 = (uint32_t*)(ws + OFF_HIST2);
    uint32_t* scal  = (uint32_t*)(ws + OFF_SCAL);
    unsigned long long* grp = (unsigned long long*)(ws + OFF_GRP);
    uint32_t* zin   = (uint32_t*)(ws + OFF_ZIN);
    unsigned long long* cand = (unsigned long long*)(ws + OFF_CAND);
    uint64_t* mask  = (uint64_t*)(ws + OFF_MASK);

    k_fused<<<dim3(NBLK), dim3(256), 0, stream>>>(logits, hist1, hist2, scal, zin, cand);
    k_rank<<<dim3(64), dim3(256), 0, stream>>>(cand, scal, deltas, locs, stridep, out);
    k_maskscan<<<dim3(500), dim3(256), 0, stream>>>(out, scal, mask, grp, zin, out);
}